// Round 1
// baseline (3240.334 us; speedup 1.0000x reference)
//
#include <hip/hip_runtime.h>
#include <hip/hip_bf16.h>
#include <stdint.h>

#define BATCH 1024
#define DIM   1024
#define HID   4096
#define TPTS  16

typedef __attribute__((ext_vector_type(8))) short  short8;
typedef __attribute__((ext_vector_type(4))) float  floatx4;

__device__ __forceinline__ unsigned short f32_to_bf16_bits(float f) {
    union { float f; unsigned u; } v; v.f = f;
    return (unsigned short)((v.u + 0x7fffu + ((v.u >> 16) & 1u)) >> 16);
}

__device__ __forceinline__ void store_bf16x4(unsigned short* p, floatx4 v) {
    union { unsigned short u[4]; uint2 q; } pk;
    pk.u[0] = f32_to_bf16_bits(v[0]);
    pk.u[1] = f32_to_bf16_bits(v[1]);
    pk.u[2] = f32_to_bf16_bits(v[2]);
    pk.u[3] = f32_to_bf16_bits(v[3]);
    *(uint2*)p = pk.q;
}

// C[M,N] = A[M,K] @ B[K,N]  with A row-major bf16 (lda), Bt = B^T row-major bf16 (ldb).
// MODE 0: fp32 out, no bias (split-K partial; blockIdx.z selects K-chunk, out += z*partStride)
// MODE 1: bf16 out = tanh(acc + bias[n]), coalesced via LDS restage
template<int MODE>
__global__ __launch_bounds__(256, 2)
void gemm_bt(const unsigned short* __restrict__ A,
             const unsigned short* __restrict__ Bt,
             const float* __restrict__ bias,
             void* __restrict__ Cout,
             int lda, int ldb, int ldc, int K, long long partStride)
{
    constexpr int LDSROW = 80;  // 32 bf16 = 64B + 16B pad (16B-aligned rows)
    __shared__ __align__(16) char smem[MODE ? 34816 : 20480];
    char* sA = smem;
    char* sB = smem + 128 * LDSROW;

    const int tid  = threadIdx.x;
    const int wave = tid >> 6;
    const int lane = tid & 63;
    const int wm = (wave >> 1) * 64;   // wave row offset in tile
    const int wn = (wave & 1) * 64;    // wave col offset in tile
    const int lr = lane & 15;
    const int q  = lane >> 4;

    const int rowBase = blockIdx.y * 128;
    const int colBase = blockIdx.x * 128;
    const long long koff = (long long)blockIdx.z * K;

    const int srow = tid >> 2;   // 0..63
    const int scol = tid & 3;    // 16B chunk within 64B row

    const unsigned short* gA0 = A + (long long)(rowBase + srow) * lda + koff + scol * 8;
    const unsigned short* gA1 = gA0 + 64LL * lda;
    const unsigned short* gB0 = Bt + (long long)(colBase + srow) * ldb + koff + scol * 8;
    const unsigned short* gB1 = gB0 + 64LL * ldb;

    char* sAw0 = sA + srow * LDSROW + scol * 16;
    char* sAw1 = sAw0 + 64 * LDSROW;
    char* sBw0 = sB + srow * LDSROW + scol * 16;
    char* sBw1 = sBw0 + 64 * LDSROW;

    floatx4 acc[4][4];
#pragma unroll
    for (int mi = 0; mi < 4; ++mi)
#pragma unroll
        for (int ni = 0; ni < 4; ++ni) {
            floatx4 z4 = {0.f, 0.f, 0.f, 0.f};
            acc[mi][ni] = z4;
        }

    uint4 ra0 = *(const uint4*)gA0;
    uint4 ra1 = *(const uint4*)gA1;
    uint4 rb0 = *(const uint4*)gB0;
    uint4 rb1 = *(const uint4*)gB1;

    const int KB = K >> 5;
    for (int kb = 0; kb < KB; ++kb) {
        if (kb) __syncthreads();
        *(uint4*)sAw0 = ra0;
        *(uint4*)sAw1 = ra1;
        *(uint4*)sBw0 = rb0;
        *(uint4*)sBw1 = rb1;
        __syncthreads();
        if (kb + 1 < KB) {  // register prefetch of next K-block overlaps MFMA below
            ra0 = *(const uint4*)(gA0 + (kb + 1) * 32);
            ra1 = *(const uint4*)(gA1 + (kb + 1) * 32);
            rb0 = *(const uint4*)(gB0 + (kb + 1) * 32);
            rb1 = *(const uint4*)(gB1 + (kb + 1) * 32);
        }
        short8 af[4], bfr[4];
#pragma unroll
        for (int mi = 0; mi < 4; ++mi)
            af[mi] = *(const short8*)(sA + (wm + mi * 16 + lr) * LDSROW + q * 16);
#pragma unroll
        for (int ni = 0; ni < 4; ++ni)
            bfr[ni] = *(const short8*)(sB + (wn + ni * 16 + lr) * LDSROW + q * 16);
#pragma unroll
        for (int mi = 0; mi < 4; ++mi)
#pragma unroll
            for (int ni = 0; ni < 4; ++ni)
                acc[mi][ni] = __builtin_amdgcn_mfma_f32_16x16x32_bf16(
                    af[mi], bfr[ni], acc[mi][ni], 0, 0, 0);
    }

    if (MODE == 0) {
        float* C = (float*)Cout + (long long)blockIdx.z * partStride;
#pragma unroll
        for (int mi = 0; mi < 4; ++mi)
#pragma unroll
            for (int ni = 0; ni < 4; ++ni) {
                const int r0 = rowBase + wm + mi * 16 + q * 4;
                const int c  = colBase + wn + ni * 16 + lr;
#pragma unroll
                for (int r = 0; r < 4; ++r)
                    C[(long long)(r0 + r) * ldc + c] = acc[mi][ni][r];
            }
    } else {
        __syncthreads();  // done reading sA/sB; reuse smem as sC
        float bias4[4];
#pragma unroll
        for (int ni = 0; ni < 4; ++ni)
            bias4[ni] = bias[colBase + wn + ni * 16 + lr];
        unsigned short* sC = (unsigned short*)smem;  // [128][136] bf16
#pragma unroll
        for (int mi = 0; mi < 4; ++mi)
#pragma unroll
            for (int ni = 0; ni < 4; ++ni)
#pragma unroll
                for (int r = 0; r < 4; ++r) {
                    const int row = wm + mi * 16 + q * 4 + r;
                    const int col = wn + ni * 16 + lr;
                    sC[row * 136 + col] =
                        f32_to_bf16_bits(tanhf(acc[mi][ni][r] + bias4[ni]));
                }
        __syncthreads();
        unsigned short* C = (unsigned short*)Cout;
#pragma unroll
        for (int it = 0; it < 8; ++it) {
            const int row = it * 16 + (tid >> 4);
            const int cc  = (tid & 15) * 8;
            *(uint4*)(C + (long long)(rowBase + row) * ldc + colBase + cc) =
                *(const uint4*)(sC + row * 136 + cc);
        }
    }
}

// k = sum_z parts[z] + b2;  RK4 state update + bf16 cast of next matmul input.
__global__ void combine(const float* __restrict__ parts,
                        const float* __restrict__ b2,
                        const float* __restrict__ ycur,
                        const float* __restrict__ tspan,
                        int step, int mode,
                        float* __restrict__ kacc,
                        unsigned short* __restrict__ ybf,
                        float* __restrict__ ynext)
{
    const int i = blockIdx.x * blockDim.x + threadIdx.x;  // over BATCH*DIM/4
    const float h = tspan[step + 1] - tspan[step];
    const int NV = BATCH * DIM / 4;
    const floatx4* p = (const floatx4*)parts;
    floatx4 k = p[i] + p[i + NV] + p[i + 2 * NV] + p[i + 3 * NV];
    k = k + *(const floatx4*)(b2 + ((i * 4) & (DIM - 1)));
    floatx4 y = ((const floatx4*)ycur)[i];
    floatx4* ka = (floatx4*)kacc;
    if (mode == 1) {
        ka[i] = k;
        store_bf16x4(ybf + i * 4, y + (0.5f * h) * k);
    } else if (mode == 2) {
        ka[i] = ka[i] + 2.0f * k;
        store_bf16x4(ybf + i * 4, y + (0.5f * h) * k);
    } else if (mode == 3) {
        ka[i] = ka[i] + 2.0f * k;
        store_bf16x4(ybf + i * 4, y + h * k);
    } else {
        floatx4 yn = y + (h * (1.0f / 6.0f)) * (ka[i] + k);
        ((floatx4*)ynext)[i] = yn;
        store_bf16x4(ybf + i * 4, yn);
    }
}

// out[c][r] = bf16(in[r][c]); in is R x C fp32.
__global__ void transpose_cast(const float* __restrict__ in,
                               unsigned short* __restrict__ out, int R, int C)
{
    __shared__ float tile[32][33];
    const int bx = blockIdx.x * 32;  // col base in 'in'
    const int by = blockIdx.y * 32;  // row base in 'in'
    const int tx = threadIdx.x, ty = threadIdx.y;  // (32, 8)
#pragma unroll
    for (int i = 0; i < 4; ++i)
        tile[ty + i * 8][tx] = in[(long long)(by + ty + i * 8) * C + bx + tx];
    __syncthreads();
#pragma unroll
    for (int i = 0; i < 4; ++i)
        out[(long long)(bx + ty + i * 8) * R + by + tx] =
            f32_to_bf16_bits(tile[tx][ty + i * 8]);
}

// d_out[0:16] = t_span; traj[0] = y_init; ybf = bf16(y_init)
__global__ void init_kernel(const float* __restrict__ y0,
                            const float* __restrict__ tspan,
                            float* __restrict__ out,
                            unsigned short* __restrict__ ybf)
{
    const int i = blockIdx.x * blockDim.x + threadIdx.x;  // over BATCH*DIM/4
    floatx4 v = ((const floatx4*)y0)[i];
    ((floatx4*)(out + TPTS))[i] = v;
    store_bf16x4(ybf + i * 4, v);
    if (blockIdx.x == 0 && threadIdx.x < TPTS) out[threadIdx.x] = tspan[threadIdx.x];
}

extern "C" void kernel_launch(void* const* d_in, const int* in_sizes, int n_in,
                              void* d_out, int out_size, void* d_ws, size_t ws_size,
                              hipStream_t stream)
{
    (void)in_sizes; (void)n_in; (void)out_size; (void)ws_size;
    const float* y0    = (const float*)d_in[0];
    const float* tspan = (const float*)d_in[1];
    const float* W1    = (const float*)d_in[2];
    const float* b1    = (const float*)d_in[3];
    const float* W2    = (const float*)d_in[4];
    const float* b2    = (const float*)d_in[5];
    float* out = (float*)d_out;

    char* ws = (char*)d_ws;
    unsigned short* W1T = (unsigned short*)(ws);                // [HID][DIM] bf16   8MB
    unsigned short* W2T = (unsigned short*)(ws + (8ll << 20));  // [DIM][HID] bf16   8MB
    unsigned short* Ybf = (unsigned short*)(ws + (16ll << 20)); // [BATCH][DIM] bf16 2MB
    unsigned short* Hbf = (unsigned short*)(ws + (18ll << 20)); // [BATCH][HID] bf16 8MB
    float* parts = (float*)(ws + (26ll << 20));                 // [4][BATCH][DIM]  16MB
    float* kacc  = (float*)(ws + (42ll << 20));                 // [BATCH][DIM]      4MB

    dim3 tb(32, 8);
    transpose_cast<<<dim3(HID / 32, DIM / 32), tb, 0, stream>>>(W1, W1T, DIM, HID);
    transpose_cast<<<dim3(DIM / 32, HID / 32), tb, 0, stream>>>(W2, W2T, HID, DIM);
    init_kernel<<<BATCH * DIM / 1024, 256, 0, stream>>>(y0, tspan, out, Ybf);

    float* traj = out + TPTS;
    for (int t = 0; t < TPTS - 1; ++t) {
        const float* ycur = traj + (long long)t * BATCH * DIM;
        float* ynext = traj + (long long)(t + 1) * BATCH * DIM;
        for (int e = 0; e < 4; ++e) {
            // H = tanh(Y @ W1 + b1)  -> bf16 [BATCH][HID]
            gemm_bt<1><<<dim3(HID / 128, BATCH / 128, 1), 256, 0, stream>>>(
                Ybf, W1T, b1, (void*)Hbf, DIM, DIM, HID, DIM, 0LL);
            // parts[z] = H[:, z*1024:+1024] @ W2[z*1024:+1024, :]  (split-K=4)
            gemm_bt<0><<<dim3(DIM / 128, BATCH / 128, 4), 256, 0, stream>>>(
                Hbf, W2T, nullptr, (void*)parts, HID, HID, DIM, HID / 4,
                (long long)BATCH * DIM);
            // k_e = sum(parts) + b2 ; RK4 update ; next Ybf
            combine<<<BATCH * DIM / 1024, 256, 0, stream>>>(
                parts, b2, ycur, tspan, t, e + 1, kacc, Ybf, ynext);
        }
    }
}

// Round 2
// 3033.579 us; speedup vs baseline: 1.0682x; 1.0682x over previous
//
#include <hip/hip_runtime.h>
#include <hip/hip_bf16.h>
#include <stdint.h>

#define BATCH 1024
#define DIM   1024
#define HID   4096
#define TPTS  16

typedef __attribute__((ext_vector_type(8))) short  short8;
typedef __attribute__((ext_vector_type(4))) float  floatx4;

__device__ __forceinline__ unsigned short f32_to_bf16_bits(float f) {
    union { float f; unsigned u; } v; v.f = f;
    return (unsigned short)((v.u + 0x7fffu + ((v.u >> 16) & 1u)) >> 16);
}

__device__ __forceinline__ void store_bf16x4(unsigned short* p, floatx4 v) {
    union { unsigned short u[4]; uint2 q; } pk;
    pk.u[0] = f32_to_bf16_bits(v[0]);
    pk.u[1] = f32_to_bf16_bits(v[1]);
    pk.u[2] = f32_to_bf16_bits(v[2]);
    pk.u[3] = f32_to_bf16_bits(v[3]);
    *(uint2*)p = pk.q;
}

// fast tanh: 1 - 2/(e^{2x}+1); saturates correctly for |x| large (exp->inf/0)
__device__ __forceinline__ float fast_tanh(float x) {
    float e = __expf(2.0f * x);
    return 1.0f - 2.0f / (e + 1.0f);
}

// async 16B global -> LDS (DMA, no VGPR round trip). LDS dest is
// wave-uniform base + lane*16 — caller guarantees lane-linear layout.
__device__ __forceinline__ void g2l16(const unsigned short* g, char* l) {
    __builtin_amdgcn_global_load_lds(
        (const __attribute__((address_space(1))) void*)g,
        (__attribute__((address_space(3))) void*)l, 16, 0, 0);
}

// C[M,N] = A[M,K] @ B[K,N]; A row-major bf16 (lda), Bt = B^T row-major bf16 (ldb).
// 128x128 tile, BK=64, 4 waves (each 64x64), global_load_lds staging with
// XOR-swizzled 16B chunks (conflict-free ds_read_b128 + HW writes).
// MODE 0: fp32 out, no bias (split-K partial; z selects K-chunk, out += z*partStride)
// MODE 1: bf16 out = tanh(acc + bias[n]), coalesced store via LDS restage
template<int MODE>
__global__ __launch_bounds__(256, 2)
void gemm_bt(const unsigned short* __restrict__ A,
             const unsigned short* __restrict__ Bt,
             const float* __restrict__ bias,
             void* __restrict__ Cout,
             int lda, int ldb, int ldc, int K, long long partStride)
{
    // sA: [128 rows][64 k] bf16 = 16KB at offset 0; sB same at 16KB.
    // Within a row (128B = 8 chunks of 16B), chunk ch holds global k-chunk
    // ch ^ (row & 7).
    __shared__ __align__(16) char smem[MODE ? 34816 : 32768];
    char* sA = smem;
    char* sB = smem + 16384;

    const int tid  = threadIdx.x;
    const int wave = tid >> 6;
    const int lane = tid & 63;
    const int wm = (wave >> 1) * 64;
    const int wn = (wave & 1) * 64;
    const int lr = lane & 15;
    const int q  = lane >> 4;

    const int rowBase = blockIdx.y * 128;
    const int colBase = blockIdx.x * 128;
    const long long koff = (long long)blockIdx.z * K;

    // --- staging addresses: 32KB / (256 thr * 16B) = 8 calls/thread.
    // calls 0..3 cover sA (16KB), 4..7 cover sB.
    const unsigned short* gp[8];
    char* lp[8];
#pragma unroll
    for (int j = 0; j < 8; ++j) {
        const int p   = (j * 256 + tid) * 16;      // byte pos in 32KB
        const int pa  = p & 16383;                 // pos within sA or sB
        const int row = pa >> 7;                   // 0..127
        const int ch  = (pa >> 4) & 7;             // 16B chunk in row
        const int sc  = ch ^ (row & 7);            // swizzle: fetch this k-chunk
        if (j < 4)
            gp[j] = A + (long long)(rowBase + row) * lda + koff + sc * 8;
        else
            gp[j] = Bt + (long long)(colBase + row) * ldb + koff + sc * 8;
        lp[j] = smem + p;
    }

    floatx4 acc[4][4];
#pragma unroll
    for (int mi = 0; mi < 4; ++mi)
#pragma unroll
        for (int ni = 0; ni < 4; ++ni) {
            floatx4 z4 = {0.f, 0.f, 0.f, 0.f};
            acc[mi][ni] = z4;
        }

    // fragment read addresses: row byte base + swizzled k-chunk
    const int xr = lr & 7;  // xor operand (row&7 == lr&7 for all frags)
    int aOff[4], bOff[4];
#pragma unroll
    for (int i = 0; i < 4; ++i) {
        aOff[i] = (wm + i * 16 + lr) * 128;
        bOff[i] = (wn + i * 16 + lr) * 128;
    }
    const int swz0 = ((0 * 4 + q) ^ xr) * 16;
    const int swz1 = ((1 * 4 + q) ^ xr) * 16;

    const int KB = K >> 6;  // BK = 64
    for (int kb = 0; kb < KB; ++kb) {
        if (kb) __syncthreads();  // all waves done reading previous tile
        const int kadv = kb * 64;
#pragma unroll
        for (int j = 0; j < 8; ++j)
            g2l16(gp[j] + kadv, lp[j]);
        __syncthreads();          // compiler drains vmcnt before barrier

        short8 af[4][2], bfr[4][2];
#pragma unroll
        for (int i = 0; i < 4; ++i) {
            af[i][0]  = *(const short8*)(sA + aOff[i] + swz0);
            af[i][1]  = *(const short8*)(sA + aOff[i] + swz1);
            bfr[i][0] = *(const short8*)(sB + bOff[i] + swz0);
            bfr[i][1] = *(const short8*)(sB + bOff[i] + swz1);
        }
#pragma unroll
        for (int g = 0; g < 2; ++g)
#pragma unroll
            for (int mi = 0; mi < 4; ++mi)
#pragma unroll
                for (int ni = 0; ni < 4; ++ni)
                    acc[mi][ni] = __builtin_amdgcn_mfma_f32_16x16x32_bf16(
                        af[mi][g], bfr[ni][g], acc[mi][ni], 0, 0, 0);
    }

    if (MODE == 0) {
        float* C = (float*)Cout + (long long)blockIdx.z * partStride;
#pragma unroll
        for (int mi = 0; mi < 4; ++mi)
#pragma unroll
            for (int ni = 0; ni < 4; ++ni) {
                const int r0 = rowBase + wm + mi * 16 + q * 4;
                const int c  = colBase + wn + ni * 16 + lr;
#pragma unroll
                for (int r = 0; r < 4; ++r)
                    C[(long long)(r0 + r) * ldc + c] = acc[mi][ni][r];
            }
    } else {
        __syncthreads();  // done reading sA/sB; reuse smem as sC
        float bias4[4];
#pragma unroll
        for (int ni = 0; ni < 4; ++ni)
            bias4[ni] = bias[colBase + wn + ni * 16 + lr];
        unsigned short* sC = (unsigned short*)smem;  // [128][136] bf16
#pragma unroll
        for (int mi = 0; mi < 4; ++mi)
#pragma unroll
            for (int ni = 0; ni < 4; ++ni)
#pragma unroll
                for (int r = 0; r < 4; ++r) {
                    const int row = wm + mi * 16 + q * 4 + r;
                    const int col = wn + ni * 16 + lr;
                    sC[row * 136 + col] =
                        f32_to_bf16_bits(fast_tanh(acc[mi][ni][r] + bias4[ni]));
                }
        __syncthreads();
        unsigned short* C = (unsigned short*)Cout;
#pragma unroll
        for (int it = 0; it < 8; ++it) {
            const int row = it * 16 + (tid >> 4);
            const int cc  = (tid & 15) * 8;
            *(uint4*)(C + (long long)(rowBase + row) * ldc + colBase + cc) =
                *(const uint4*)(sC + row * 136 + cc);
        }
    }
}

// k = sum_z parts[z] + b2;  RK4 state update + bf16 cast of next matmul input.
__global__ void combine(const float* __restrict__ parts,
                        const float* __restrict__ b2,
                        const float* __restrict__ ycur,
                        const float* __restrict__ tspan,
                        int step, int mode,
                        float* __restrict__ kacc,
                        unsigned short* __restrict__ ybf,
                        float* __restrict__ ynext)
{
    const int i = blockIdx.x * blockDim.x + threadIdx.x;  // over BATCH*DIM/4
    const float h = tspan[step + 1] - tspan[step];
    const int NV = BATCH * DIM / 4;
    const floatx4* p = (const floatx4*)parts;
    floatx4 k = p[i] + p[i + NV] + p[i + 2 * NV] + p[i + 3 * NV];
    k = k + *(const floatx4*)(b2 + ((i * 4) & (DIM - 1)));
    floatx4 y = ((const floatx4*)ycur)[i];
    floatx4* ka = (floatx4*)kacc;
    if (mode == 1) {
        ka[i] = k;
        store_bf16x4(ybf + i * 4, y + (0.5f * h) * k);
    } else if (mode == 2) {
        ka[i] = ka[i] + 2.0f * k;
        store_bf16x4(ybf + i * 4, y + (0.5f * h) * k);
    } else if (mode == 3) {
        ka[i] = ka[i] + 2.0f * k;
        store_bf16x4(ybf + i * 4, y + h * k);
    } else {
        floatx4 yn = y + (h * (1.0f / 6.0f)) * (ka[i] + k);
        ((floatx4*)ynext)[i] = yn;
        store_bf16x4(ybf + i * 4, yn);
    }
}

// out[c][r] = bf16(in[r][c]); in is R x C fp32.
__global__ void transpose_cast(const float* __restrict__ in,
                               unsigned short* __restrict__ out, int R, int C)
{
    __shared__ float tile[32][33];
    const int bx = blockIdx.x * 32;  // col base in 'in'
    const int by = blockIdx.y * 32;  // row base in 'in'
    const int tx = threadIdx.x, ty = threadIdx.y;  // (32, 8)
#pragma unroll
    for (int i = 0; i < 4; ++i)
        tile[ty + i * 8][tx] = in[(long long)(by + ty + i * 8) * C + bx + tx];
    __syncthreads();
#pragma unroll
    for (int i = 0; i < 4; ++i)
        out[(long long)(bx + ty + i * 8) * R + by + tx] =
            f32_to_bf16_bits(tile[tx][ty + i * 8]);
}

// d_out[0:16] = t_span; traj[0] = y_init; ybf = bf16(y_init)
__global__ void init_kernel(const float* __restrict__ y0,
                            const float* __restrict__ tspan,
                            float* __restrict__ out,
                            unsigned short* __restrict__ ybf)
{
    const int i = blockIdx.x * blockDim.x + threadIdx.x;  // over BATCH*DIM/4
    floatx4 v = ((const floatx4*)y0)[i];
    ((floatx4*)(out + TPTS))[i] = v;
    store_bf16x4(ybf + i * 4, v);
    if (blockIdx.x == 0 && threadIdx.x < TPTS) out[threadIdx.x] = tspan[threadIdx.x];
}

extern "C" void kernel_launch(void* const* d_in, const int* in_sizes, int n_in,
                              void* d_out, int out_size, void* d_ws, size_t ws_size,
                              hipStream_t stream)
{
    (void)in_sizes; (void)n_in; (void)out_size; (void)ws_size;
    const float* y0    = (const float*)d_in[0];
    const float* tspan = (const float*)d_in[1];
    const float* W1    = (const float*)d_in[2];
    const float* b1    = (const float*)d_in[3];
    const float* W2    = (const float*)d_in[4];
    const float* b2    = (const float*)d_in[5];
    float* out = (float*)d_out;

    char* ws = (char*)d_ws;
    unsigned short* W1T = (unsigned short*)(ws);                // [HID][DIM] bf16   8MB
    unsigned short* W2T = (unsigned short*)(ws + (8ll << 20));  // [DIM][HID] bf16   8MB
    unsigned short* Ybf = (unsigned short*)(ws + (16ll << 20)); // [BATCH][DIM] bf16 2MB
    unsigned short* Hbf = (unsigned short*)(ws + (18ll << 20)); // [BATCH][HID] bf16 8MB
    float* parts = (float*)(ws + (26ll << 20));                 // [4][BATCH][DIM]  16MB
    float* kacc  = (float*)(ws + (42ll << 20));                 // [BATCH][DIM]      4MB

    dim3 tb(32, 8);
    transpose_cast<<<dim3(HID / 32, DIM / 32), tb, 0, stream>>>(W1, W1T, DIM, HID);
    transpose_cast<<<dim3(DIM / 32, HID / 32), tb, 0, stream>>>(W2, W2T, HID, DIM);
    init_kernel<<<BATCH * DIM / 1024, 256, 0, stream>>>(y0, tspan, out, Ybf);

    float* traj = out + TPTS;
    for (int t = 0; t < TPTS - 1; ++t) {
        const float* ycur = traj + (long long)t * BATCH * DIM;
        float* ynext = traj + (long long)(t + 1) * BATCH * DIM;
        for (int e = 0; e < 4; ++e) {
            // H = tanh(Y @ W1 + b1)  -> bf16 [BATCH][HID]
            gemm_bt<1><<<dim3(HID / 128, BATCH / 128, 1), 256, 0, stream>>>(
                Ybf, W1T, b1, (void*)Hbf, DIM, DIM, HID, DIM, 0LL);
            // parts[z] = H[:, z*1024:+1024] @ W2[z*1024:+1024, :]  (split-K=4)
            gemm_bt<0><<<dim3(DIM / 128, BATCH / 128, 4), 256, 0, stream>>>(
                Hbf, W2T, nullptr, (void*)parts, HID, HID, DIM, HID / 4,
                (long long)BATCH * DIM);
            // k_e = sum(parts) + b2 ; RK4 update ; next Ybf
            combine<<<BATCH * DIM / 1024, 256, 0, stream>>>(
                parts, b2, ycur, tspan, t, e + 1, kacc, Ybf, ynext);
        }
    }
}